// Round 7
// baseline (107.921 us; speedup 1.0000x reference)
//
#include <hip/hip_runtime.h>

#define HH 384
#define WW 384
#define HWP (HH * WW)   // 147456
#define DD 64
#define BB 2
#define NG 16           // 16 groups of 4 channels

#define TX 64
#define TY 4
#define LR 20           // TY + 16 halo rows
#define LC 80           // TX + 16 halo cols
#define LN (LR * LC)    // 1600 slots
#define NBX 6
#define NBY 96
#define NWG (NBX * NBY * BB)   // 1152 = 8 * 144

typedef __fp16 h2v __attribute__((ext_vector_type(2)));
union h4 { uint2 u; h2v h[2]; };

#if __has_builtin(__builtin_amdgcn_fdot2)
#define DOT4(acc, a, b)                                           \
    acc = __builtin_amdgcn_fdot2((a).h[0], (b).h[0], acc, false);   \
    acc = __builtin_amdgcn_fdot2((a).h[1], (b).h[1], acc, false)
#else
#define DOT4(acc, a, b)                                     \
    acc = fmaf((float)(a).h[0].x, (float)(b).h[0].x, acc);   \
    acc = fmaf((float)(a).h[0].y, (float)(b).h[0].y, acc);   \
    acc = fmaf((float)(a).h[1].x, (float)(b).h[1].x, acc);   \
    acc = fmaf((float)(a).h[1].y, (float)(b).h[1].y, acc)
#endif

// K1: stats + repack to f16 channel-group planes hp[b][g][y][x] (8 B / px / group)
__global__ __launch_bounds__(256) void stats_pack_k(const float* __restrict__ des,
                                                    uint2* __restrict__ hp,
                                                    float* __restrict__ ssq,
                                                    float* __restrict__ smm) {
    int idx = blockIdx.x * 256 + threadIdx.x;        // 0 .. 294911
    int b = idx / HWP;
    int p = idx - b * HWP;
    const float* base = des + (size_t)b * DD * HWP + p;
    uint2* hb = hp + (size_t)b * NG * HWP + p;
    float ss = 0.f, s0 = 0.f;
#pragma unroll 4
    for (int g = 0; g < NG; ++g) {
        float vx = base[(size_t)(4 * g + 0) * HWP];
        float vy = base[(size_t)(4 * g + 1) * HWP];
        float vz = base[(size_t)(4 * g + 2) * HWP];
        float vw = base[(size_t)(4 * g + 3) * HWP];
        ss = fmaf(vx, vx, ss); ss = fmaf(vy, vy, ss);
        ss = fmaf(vz, vz, ss); ss = fmaf(vw, vw, ss);
        s0 += (vx + vy) + (vz + vw);
        h4 h;
        h.h[0] = __builtin_amdgcn_cvt_pkrtz(vx, vy);
        h.h[1] = __builtin_amdgcn_cvt_pkrtz(vz, vw);
        hb[(size_t)g * HWP] = h.u;
    }
    ssq[idx] = ss;
    smm[idx] = s0;
}

// K2: dilated 5x5 dot stencil on packed f16 planes. 1 px/thread, tile 64x4,
// f16 LDS double-buffer, 16 phases.
__global__ __launch_bounds__(256, 4) void ssd_k(const uint2* __restrict__ hp,
                                                const float* __restrict__ ssq,
                                                const float* __restrict__ smm,
                                                float* __restrict__ out) {
    __shared__ h4 lds[2][LN];   // 25,600 B
    const int tx = threadIdx.x;            // 0..63
    const int ty = threadIdx.y;            // 0..3
    const int tid = ty * 64 + tx;

    // XCD-aware bijective swizzle (1152 = 8 * 144)
    int bid = blockIdx.x;
    int swz = (bid & 7) * 144 + (bid >> 3);
    int b  = swz / (NBX * NBY);
    int r0 = swz % (NBX * NBY);
    int by = r0 / NBX;
    int bx = r0 - by * NBX;
    const int x0 = bx * TX, y0 = by * TY;
    const int x = x0 + tx;
    const int y = y0 + ty;

    // Clamped global offsets for this thread's 7 staging slots (1600 = 6*256 + 64)
    int goff[7];
#pragma unroll
    for (int k = 0; k < 7; ++k) {
        int i = tid + 256 * k;
        if (i < LN) {
            int r = i / LC, c = i - (i / LC) * LC;
            int gy = y0 + r - 8; gy = gy < 0 ? 0 : (gy > HH - 1 ? HH - 1 : gy);
            int gx = x0 + c - 8; gx = gx < 0 ? 0 : (gx > WW - 1 ? WW - 1 : gx);
            goff[k] = gy * WW + gx;
        } else {
            goff[k] = 0;
        }
    }

    const uint2* hb = hp + (size_t)b * NG * HWP;
    uint2 rg[7];

    auto ISSUE = [&](int g) {
        const uint2* p = hb + (size_t)g * HWP;
#pragma unroll
        for (int k = 0; k < 7; ++k) rg[k] = p[goff[k]];
    };
    auto FIN = [&](int bb) {
#pragma unroll
        for (int k = 0; k < 6; ++k) lds[bb][tid + 256 * k].u = rg[k];
        if (tid < LN - 1536) lds[bb][tid + 1536].u = rg[6];
    };

    float acc[25];
#pragma unroll
    for (int n = 0; n < 25; ++n) acc[n] = 0.f;

    const int base = ty * LC + tx;
    auto COMPUTE = [&](int bb) {
        const h4* L = lds[bb];
        h4 c = L[base + 8 * LC + 8];       // center (m=2,j=2)
#pragma unroll
        for (int m = 0; m < 5; ++m)
#pragma unroll
            for (int j = 0; j < 5; ++j) {
                h4 v = L[base + (4 * m) * LC + 4 * j];
                DOT4(acc[m * 5 + j], c, v);
            }
    };

    ISSUE(0);
    FIN(0);
    __syncthreads();
    for (int g = 0; g < NG; g += 2) {
        ISSUE(g + 1);
        COMPUTE(0);
        FIN(1);
        __syncthreads();
        if (g + 2 < NG) ISSUE(g + 2);
        COMPUTE(1);
        if (g + 2 < NG) FIN(0);
        __syncthreads();
    }

    // epilogue: stage ssq tile (f32) into buffer 0
    float* lsq = (float*)&lds[0][0];   // 1600 floats (6.4 KB)
    {
        const float* sp = ssq + (size_t)b * HWP;
        float r[7];
#pragma unroll
        for (int k = 0; k < 7; ++k) r[k] = sp[goff[k]];
#pragma unroll
        for (int k = 0; k < 6; ++k) lsq[tid + 256 * k] = r[k];
        if (tid < LN - 1536) lsq[tid + 1536] = r[6];
    }
    __syncthreads();

    // clamped tap coords for exact-zero self taps
    int yc[5], xc[5];
#pragma unroll
    for (int m = 0; m < 5; ++m) {
        int yy = y - 8 + 4 * m; yc[m] = yy < 0 ? 0 : (yy > HH - 1 ? HH - 1 : yy);
        int xx = x - 8 + 4 * m; xc[m] = xx < 0 ? 0 : (xx > WW - 1 ? WW - 1 : xx);
    }

    float ssA = lsq[base + 8 * LC + 8];
    float mu = smm[(size_t)b * HWP + y * WW + x] * (1.0f / 64);
    float var = ssA * (1.0f / 64) - mu * mu;
    float sabs = sqrtf(fmaxf(var, 0.f));
    float L = 0.f;
#pragma unroll
    for (int m = 0; m < 5; ++m)
#pragma unroll
        for (int j = 0; j < 5; ++j) {
            float ssB = lsq[base + (4 * m) * LC + 4 * j];
            float d2 = fmaxf(ssA + ssB - 2.f * acc[m * 5 + j], 0.f);
            float sq = sqrtf(d2);
            L += (yc[m] == y && xc[j] == x) ? 0.f : sq;
        }
    float srel = L * (1.0f / 25);
    float sraw = sabs * srel;
    out[(size_t)b * HWP + y * WW + x] = sraw / (sraw + 1.f);
}

extern "C" void kernel_launch(void* const* d_in, const int* in_sizes, int n_in,
                              void* d_out, int out_size, void* d_ws, size_t ws_size,
                              hipStream_t stream) {
    const float* des = (const float*)d_in[0];
    float* out = (float*)d_out;

    uint2* hp  = (uint2*)d_ws;                                   // BB*NG*HWP uint2
    float* ssq = (float*)(hp + (size_t)BB * NG * HWP);           // BB*HWP
    float* smm = ssq + (size_t)BB * HWP;                         // BB*HWP

    stats_pack_k<<<dim3((BB * HWP) / 256), dim3(256), 0, stream>>>(des, hp, ssq, smm);
    ssd_k<<<dim3(NWG), dim3(64, 4), 0, stream>>>(hp, ssq, smm, out);
}

// Round 8
// 65.448 us; speedup vs baseline: 1.6490x; 1.6490x over previous
//
#include <hip/hip_runtime.h>

#define HH 384
#define WW 384
#define HWP (HH * WW)   // 147456
#define DD 64
#define BB 2
#define NG 16           // 16 groups of 4 channels

#define TX 64
#define TY 4
#define LR 20           // TY + 16 halo rows
#define LC 80           // TX + 16 halo cols
#define LN (LR * LC)    // 1600 slots
#define NBX 6
#define NBY 96
#define NWG (NBX * NBY * BB)   // 1152 = 8 * 144

typedef __fp16 h2v __attribute__((ext_vector_type(2)));
union h4 { uint2 u; h2v h[2]; };

#if __has_builtin(__builtin_amdgcn_fdot2)
#define DOT4(acc, a, b)                                           \
    acc = __builtin_amdgcn_fdot2((a).h[0], (b).h[0], acc, false);   \
    acc = __builtin_amdgcn_fdot2((a).h[1], (b).h[1], acc, false)
#else
#define DOT4(acc, a, b)                                     \
    acc = fmaf((float)(a).h[0].x, (float)(b).h[0].x, acc);   \
    acc = fmaf((float)(a).h[0].y, (float)(b).h[0].y, acc);   \
    acc = fmaf((float)(a).h[1].x, (float)(b).h[1].x, acc);   \
    acc = fmaf((float)(a).h[1].y, (float)(b).h[1].y, acc)
#endif

// K1: stats + repack to f16 channel-group planes hp[b][g][y][x] (8 B / px / group)
__global__ __launch_bounds__(256) void stats_pack_k(const float* __restrict__ des,
                                                    uint2* __restrict__ hp,
                                                    float* __restrict__ ssq,
                                                    float* __restrict__ smm) {
    int idx = blockIdx.x * 256 + threadIdx.x;        // 0 .. 294911
    int b = idx / HWP;
    int p = idx - b * HWP;
    const float* base = des + (size_t)b * DD * HWP + p;
    uint2* hb = hp + (size_t)b * NG * HWP + p;
    float ss = 0.f, s0 = 0.f;
#pragma unroll 4
    for (int g = 0; g < NG; ++g) {
        float vx = base[(size_t)(4 * g + 0) * HWP];
        float vy = base[(size_t)(4 * g + 1) * HWP];
        float vz = base[(size_t)(4 * g + 2) * HWP];
        float vw = base[(size_t)(4 * g + 3) * HWP];
        ss = fmaf(vx, vx, ss); ss = fmaf(vy, vy, ss);
        ss = fmaf(vz, vz, ss); ss = fmaf(vw, vw, ss);
        s0 += (vx + vy) + (vz + vw);
        h4 h;
        h.h[0] = __builtin_amdgcn_cvt_pkrtz(vx, vy);
        h.h[1] = __builtin_amdgcn_cvt_pkrtz(vz, vw);
        hb[(size_t)g * HWP] = h.u;
    }
    ssq[idx] = ss;
    smm[idx] = s0;
}

// K2: dilated 5x5 dot stencil on packed f16 planes. 1 px/thread, tile 64x4,
// f16 LDS double-buffer, 16 phases. NO waves/EU clamp (R7's =4 caused 64-VGPR
// squeeze -> 138 MB scratch spill traffic).
__global__ __launch_bounds__(256) void ssd_k(const uint2* __restrict__ hp,
                                             const float* __restrict__ ssq,
                                             const float* __restrict__ smm,
                                             float* __restrict__ out) {
    __shared__ h4 lds[2][LN];   // 25,600 B
    const int tx = threadIdx.x;            // 0..63
    const int ty = threadIdx.y;            // 0..3
    const int tid = ty * 64 + tx;

    // XCD-aware bijective swizzle (1152 = 8 * 144)
    int bid = blockIdx.x;
    int swz = (bid & 7) * 144 + (bid >> 3);
    int b  = swz / (NBX * NBY);
    int r0 = swz % (NBX * NBY);
    int by = r0 / NBX;
    int bx = r0 - by * NBX;
    const int x0 = bx * TX, y0 = by * TY;
    const int x = x0 + tx;
    const int y = y0 + ty;

    // Clamped global offsets for this thread's 7 staging slots (1600 = 6*256 + 64)
    int goff[7];
#pragma unroll
    for (int k = 0; k < 7; ++k) {
        int i = tid + 256 * k;
        if (i < LN) {
            int r = i / LC, c = i - (i / LC) * LC;
            int gy = y0 + r - 8; gy = gy < 0 ? 0 : (gy > HH - 1 ? HH - 1 : gy);
            int gx = x0 + c - 8; gx = gx < 0 ? 0 : (gx > WW - 1 ? WW - 1 : gx);
            goff[k] = gy * WW + gx;
        } else {
            goff[k] = 0;
        }
    }

    const uint2* hb = hp + (size_t)b * NG * HWP;
    uint2 rg[7];

    auto ISSUE = [&](int g) {
        const uint2* p = hb + (size_t)g * HWP;
#pragma unroll
        for (int k = 0; k < 7; ++k) rg[k] = p[goff[k]];
    };
    auto FIN = [&](int bb) {
#pragma unroll
        for (int k = 0; k < 6; ++k) lds[bb][tid + 256 * k].u = rg[k];
        if (tid < LN - 1536) lds[bb][tid + 1536].u = rg[6];
    };

    float acc[25];
#pragma unroll
    for (int n = 0; n < 25; ++n) acc[n] = 0.f;

    const int base = ty * LC + tx;
    auto COMPUTE = [&](int bb) {
        const h4* L = lds[bb];
        h4 c = L[base + 8 * LC + 8];       // center (m=2,j=2)
#pragma unroll
        for (int m = 0; m < 5; ++m)
#pragma unroll
            for (int j = 0; j < 5; ++j) {
                h4 v = L[base + (4 * m) * LC + 4 * j];
                DOT4(acc[m * 5 + j], c, v);
            }
    };

    ISSUE(0);
    FIN(0);
    __syncthreads();
    for (int g = 0; g < NG; g += 2) {
        ISSUE(g + 1);
        COMPUTE(0);
        FIN(1);
        __syncthreads();
        if (g + 2 < NG) ISSUE(g + 2);
        COMPUTE(1);
        if (g + 2 < NG) FIN(0);
        __syncthreads();
    }

    // epilogue: stage ssq tile (f32) into buffer 0
    float* lsq = (float*)&lds[0][0];   // 1600 floats (6.4 KB)
    {
        const float* sp = ssq + (size_t)b * HWP;
        float r[7];
#pragma unroll
        for (int k = 0; k < 7; ++k) r[k] = sp[goff[k]];
#pragma unroll
        for (int k = 0; k < 6; ++k) lsq[tid + 256 * k] = r[k];
        if (tid < LN - 1536) lsq[tid + 1536] = r[6];
    }
    __syncthreads();

    // clamped tap coords for exact-zero self taps
    int yc[5], xc[5];
#pragma unroll
    for (int m = 0; m < 5; ++m) {
        int yy = y - 8 + 4 * m; yc[m] = yy < 0 ? 0 : (yy > HH - 1 ? HH - 1 : yy);
        int xx = x - 8 + 4 * m; xc[m] = xx < 0 ? 0 : (xx > WW - 1 ? WW - 1 : xx);
    }

    float ssA = lsq[base + 8 * LC + 8];
    float mu = smm[(size_t)b * HWP + y * WW + x] * (1.0f / 64);
    float var = ssA * (1.0f / 64) - mu * mu;
    float sabs = sqrtf(fmaxf(var, 0.f));
    float L = 0.f;
#pragma unroll
    for (int m = 0; m < 5; ++m)
#pragma unroll
        for (int j = 0; j < 5; ++j) {
            float ssB = lsq[base + (4 * m) * LC + 4 * j];
            float d2 = fmaxf(ssA + ssB - 2.f * acc[m * 5 + j], 0.f);
            float sq = sqrtf(d2);
            L += (yc[m] == y && xc[j] == x) ? 0.f : sq;
        }
    float srel = L * (1.0f / 25);
    float sraw = sabs * srel;
    out[(size_t)b * HWP + y * WW + x] = sraw / (sraw + 1.f);
}

extern "C" void kernel_launch(void* const* d_in, const int* in_sizes, int n_in,
                              void* d_out, int out_size, void* d_ws, size_t ws_size,
                              hipStream_t stream) {
    const float* des = (const float*)d_in[0];
    float* out = (float*)d_out;

    uint2* hp  = (uint2*)d_ws;                                   // BB*NG*HWP uint2
    float* ssq = (float*)(hp + (size_t)BB * NG * HWP);           // BB*HWP
    float* smm = ssq + (size_t)BB * HWP;                         // BB*HWP

    stats_pack_k<<<dim3((BB * HWP) / 256), dim3(256), 0, stream>>>(des, hp, ssq, smm);
    ssd_k<<<dim3(NWG), dim3(64, 4), 0, stream>>>(hp, ssq, smm, out);
}